// Round 2
// baseline (1474.913 us; speedup 1.0000x reference)
//
#include <hip/hip_runtime.h>
#include <math.h>

#define BB 4
#define SS 4096
#define DD 1024
#define HH 16
#define HDD 64
#define MM (BB*SS)   // 16384
#define EPSV 1e-6f

// ---------------- zero scratch (kv/ksum) ----------------
__global__ void zero_kernel(float* __restrict__ p, int n) {
    int i = blockIdx.x * blockDim.x + threadIdx.x;
    if (i < n) p[i] = 0.0f;
}

// ---------------- fused QKV projection GEMM ----------------
// C[M=16384, N=1024] = hs @ W + bias, epilogue elu+1 for q,k.
// grid: (N/128, M/128, 3), block 256, tile 128x128x8, 8x8 per thread.
__global__ __launch_bounds__(256) void qkv_gemm(
    const float* __restrict__ hs,
    const float* __restrict__ Wq, const float* __restrict__ bq,
    const float* __restrict__ Wk, const float* __restrict__ bk,
    const float* __restrict__ Wv, const float* __restrict__ bv,
    float* __restrict__ qf, float* __restrict__ kf, float* __restrict__ vf)
{
    const int which = blockIdx.z;
    const float* __restrict__ W    = (which == 0) ? Wq : (which == 1) ? Wk : Wv;
    const float* __restrict__ bias = (which == 0) ? bq : (which == 1) ? bk : bv;
    float* __restrict__ out        = (which == 0) ? qf : (which == 1) ? kf : vf;

    const int n0 = blockIdx.x * 128;
    const int m0 = blockIdx.y * 128;

    __shared__ float As[8][128];   // As[k][m]
    __shared__ float Bs[8][128];   // Bs[k][n]

    const int tid = threadIdx.x;
    const int tx = tid & 15;       // 0..15 -> col group
    const int ty = tid >> 4;       // 0..15 -> row group

    float acc[8][8];
#pragma unroll
    for (int i = 0; i < 8; i++)
#pragma unroll
        for (int j = 0; j < 8; j++) acc[i][j] = 0.f;

    // A load: thread t -> row t/2, k-col (t&1)*4 (one float4)
    const int a_row = tid >> 1;
    const int a_kc  = (tid & 1) * 4;
    // B load: thread t -> k t/32, n-col (t&31)*4 (one float4)
    const int b_k  = tid >> 5;
    const int b_nc = (tid & 31) * 4;

    for (int k0 = 0; k0 < DD; k0 += 8) {
        float4 av = *reinterpret_cast<const float4*>(&hs[(size_t)(m0 + a_row) * DD + k0 + a_kc]);
        float4 bw = *reinterpret_cast<const float4*>(&W[(size_t)(k0 + b_k) * DD + n0 + b_nc]);
        __syncthreads();
        As[a_kc + 0][a_row] = av.x;
        As[a_kc + 1][a_row] = av.y;
        As[a_kc + 2][a_row] = av.z;
        As[a_kc + 3][a_row] = av.w;
        *reinterpret_cast<float4*>(&Bs[b_k][b_nc]) = bw;
        __syncthreads();
#pragma unroll
        for (int kk = 0; kk < 8; kk++) {
            float a[8], b[8];
#pragma unroll
            for (int i = 0; i < 8; i++) a[i] = As[kk][ty * 8 + i];
#pragma unroll
            for (int j = 0; j < 8; j++) b[j] = Bs[kk][tx * 8 + j];
#pragma unroll
            for (int i = 0; i < 8; i++)
#pragma unroll
                for (int j = 0; j < 8; j++)
                    acc[i][j] += a[i] * b[j];
        }
    }

    const bool is_qk = (which < 2);
#pragma unroll
    for (int i = 0; i < 8; i++) {
        const int m = m0 + ty * 8 + i;
#pragma unroll
        for (int jg = 0; jg < 2; jg++) {
            float4 c4;
            float* cp = &c4.x;
#pragma unroll
            for (int j = 0; j < 4; j++) {
                const int n = n0 + tx * 8 + jg * 4 + j;
                float c = acc[i][jg * 4 + j] + bias[n];
                if (is_qk) c = (c > 0.f) ? (c + 1.f) : __expf(c);
                cp[j] = c;
            }
            *reinterpret_cast<float4*>(&out[(size_t)m * DD + n0 + tx * 8 + jg * 4]) = c4;
        }
    }
}

// ---------------- kv[b,h,d,e] = sum_s k[s,d]*v[s,e]; ksum[b,h,d] ----------------
// grid: (B*H, 8 chunks), block 256; 4x4 per thread of the 64x64 kv tile.
__global__ __launch_bounds__(256) void kv_ksum_kernel(
    const float* __restrict__ kf, const float* __restrict__ vf,
    float* __restrict__ kv, float* __restrict__ ksum)
{
    const int bh = blockIdx.x;      // 0..63
    const int chunk = blockIdx.y;   // 0..7
    const int b = bh / HH, h = bh % HH;
    const int s0 = chunk * (SS / 8);

    __shared__ float kbuf[16][64];
    __shared__ float vbuf[16][64];

    const int tid = threadIdx.x;
    const int tx = tid & 15;        // e group
    const int ty = tid >> 4;        // d group

    float acc[4][4] = {};
    float ks[4] = {};

    const size_t base = (size_t)b * SS * DD + (size_t)h * HDD;

    for (int s = s0; s < s0 + SS / 8; s += 16) {
        __syncthreads();
        {
            const int r = ty;            // 0..15
            const int c0 = tx * 4;
            *reinterpret_cast<float4*>(&kbuf[r][c0]) =
                *reinterpret_cast<const float4*>(&kf[base + (size_t)(s + r) * DD + c0]);
            *reinterpret_cast<float4*>(&vbuf[r][c0]) =
                *reinterpret_cast<const float4*>(&vf[base + (size_t)(s + r) * DD + c0]);
        }
        __syncthreads();
#pragma unroll
        for (int ss = 0; ss < 16; ss++) {
            float a[4], bb[4];
#pragma unroll
            for (int i = 0; i < 4; i++) a[i] = kbuf[ss][ty * 4 + i];
#pragma unroll
            for (int j = 0; j < 4; j++) bb[j] = vbuf[ss][tx * 4 + j];
#pragma unroll
            for (int i = 0; i < 4; i++)
#pragma unroll
                for (int j = 0; j < 4; j++)
                    acc[i][j] += a[i] * bb[j];
            if (tx == 0) {
#pragma unroll
                for (int i = 0; i < 4; i++) ks[i] += a[i];
            }
        }
    }

    float* kvp = kv + (size_t)bh * HDD * HDD;
#pragma unroll
    for (int i = 0; i < 4; i++)
#pragma unroll
        for (int j = 0; j < 4; j++)
            atomicAdd(&kvp[(ty * 4 + i) * HDD + tx * 4 + j], acc[i][j]);
    if (tx == 0) {
#pragma unroll
        for (int i = 0; i < 4; i++)
            atomicAdd(&ksum[bh * HDD + ty * 4 + i], ks[i]);
    }
}

// ---------------- out = (q_feat @ kv) / max(q_feat . ksum, eps) ----------------
// grid: (B*H, S/64), block 256 (4 waves x 16 rows). q_feat lives in d_out;
// each block stages its own 64x64 patch into LDS then overwrites it in place.
__global__ __launch_bounds__(256) void out_kernel(
    const float* __restrict__ kv, const float* __restrict__ ksum,
    float* __restrict__ qf_out)
{
    const int bh = blockIdx.x;
    const int sblk = blockIdx.y;
    const int b = bh / HH, h = bh % HH;
    const int s0 = sblk * 64;

    __shared__ float kvs[64][64];
    __shared__ float kss[64];
    __shared__ float qs[64][64];

    const int tid = threadIdx.x;

    {   // kv tile: 4096 floats, 4 float4 per thread
        const float* kvp = kv + (size_t)bh * HDD * HDD;
        float* kvf = &kvs[0][0];
#pragma unroll
        for (int it = 0; it < 4; it++) {
            const int i = tid * 4 + it * 1024;
            *reinterpret_cast<float4*>(&kvf[i]) = *reinterpret_cast<const float4*>(&kvp[i]);
        }
        if (tid < 64) kss[tid] = ksum[bh * HDD + tid];
    }
    const size_t base = (size_t)(b * SS + s0) * DD + (size_t)h * HDD;
    {   // q tile: rows s0..s0+63, cols h*64..h*64+63
        const int r = tid >> 4;          // 0..15
        const int c0 = (tid & 15) * 4;
#pragma unroll
        for (int rg = 0; rg < 64; rg += 16) {
            *reinterpret_cast<float4*>(&qs[r + rg][c0]) =
                *reinterpret_cast<const float4*>(&qf_out[base + (size_t)(r + rg) * DD + c0]);
        }
    }
    __syncthreads();

    const int lane = tid & 63;
    const int wv = tid >> 6;             // 0..3

    for (int si = wv * 16; si < wv * 16 + 16; si++) {
        float num = 0.f, den = 0.f;
#pragma unroll
        for (int d = 0; d < 64; d++) {
            const float q = qs[si][d];
            num += q * kvs[d][lane];
            den += q * kss[d];
        }
        den = fmaxf(den, EPSV);
        qf_out[base + (size_t)si * DD + lane] = num / den;
    }
}

extern "C" void kernel_launch(void* const* d_in, const int* in_sizes, int n_in,
                              void* d_out, int out_size, void* d_ws, size_t ws_size,
                              hipStream_t stream) {
    const float* hs = (const float*)d_in[0];
    const float* Wq = (const float*)d_in[1];
    const float* bq = (const float*)d_in[2];
    const float* Wk = (const float*)d_in[3];
    const float* bk = (const float*)d_in[4];
    const float* Wv = (const float*)d_in[5];
    const float* bv = (const float*)d_in[6];
    float* out = (float*)d_out;

    // q_feat goes straight into d_out (same [M,D] layout, consumed in-place).
    float* qf   = out;
    float* kf   = (float*)d_ws;                    // 64 MB
    float* vf   = kf + (size_t)MM * DD;            // 64 MB
    float* kvp  = vf + (size_t)MM * DD;            // 1 MB
    float* ksum = kvp + (size_t)BB * HH * HDD * HDD; // 16 KB

    const int nz = BB * HH * HDD * HDD + BB * HH * HDD;
    hipLaunchKernelGGL(zero_kernel, dim3((nz + 255) / 256), dim3(256), 0, stream, kvp, nz);

    dim3 g1(DD / 128, MM / 128, 3);
    hipLaunchKernelGGL(qkv_gemm, g1, dim3(256), 0, stream,
                       hs, Wq, bq, Wk, bk, Wv, bv, qf, kf, vf);

    dim3 g2(BB * HH, 8);
    hipLaunchKernelGGL(kv_ksum_kernel, g2, dim3(256), 0, stream, kf, vf, kvp, ksum);

    dim3 g3(BB * HH, SS / 64);
    hipLaunchKernelGGL(out_kernel, g3, dim3(256), 0, stream, kvp, ksum, out);
}

// Round 5
// 371.038 us; speedup vs baseline: 3.9751x; 3.9751x over previous
//
#include <hip/hip_runtime.h>
#include <math.h>

#define BB 4
#define SS 4096
#define DD 1024
#define HH 16
#define HDD 64
#define MM (BB*SS)   // 16384
#define EPSV 1e-6f

typedef __bf16 bf16x8 __attribute__((ext_vector_type(8)));
typedef float  f32x4  __attribute__((ext_vector_type(4)));
typedef unsigned short ushort_t;

__device__ __forceinline__ float bf2f(unsigned int u16) {
    unsigned int x = u16 << 16;
    return __uint_as_float(x);
}
__device__ __forceinline__ unsigned short f2bf(float f) {
    unsigned int x = __float_as_uint(f);
    unsigned int r = x + 0x7fffu + ((x >> 16) & 1u);  // RNE
    return (unsigned short)(r >> 16);
}

#define GLDS16(g, l) __builtin_amdgcn_global_load_lds( \
    (const __attribute__((address_space(1))) void*)(g), \
    (__attribute__((address_space(3))) void*)(l), 16, 0, 0)

// ---------------- zero scratch (kv/ksum fp32 accumulators) ----------------
__global__ void zero_kernel(float* __restrict__ p, int n) {
    int i = blockIdx.x * blockDim.x + threadIdx.x;
    if (i < n) p[i] = 0.0f;
}

// ---------------- hs fp32 -> bf16 (row-major unchanged) ----------------
__global__ __launch_bounds__(256) void cvt_hs(const float* __restrict__ in,
                                              ushort_t* __restrict__ out) {
    size_t i = ((size_t)blockIdx.x * 256 + threadIdx.x) * 8;
    float4 f0 = *reinterpret_cast<const float4*>(&in[i]);
    float4 f1 = *reinterpret_cast<const float4*>(&in[i + 4]);
    uint4 u;
    u.x = (unsigned)f2bf(f0.x) | ((unsigned)f2bf(f0.y) << 16);
    u.y = (unsigned)f2bf(f0.z) | ((unsigned)f2bf(f0.w) << 16);
    u.z = (unsigned)f2bf(f1.x) | ((unsigned)f2bf(f1.y) << 16);
    u.w = (unsigned)f2bf(f1.z) | ((unsigned)f2bf(f1.w) << 16);
    *reinterpret_cast<uint4*>(&out[i]) = u;
}

// ---------------- W [K][N] fp32 -> Wt [z][N][K] bf16 (transposed) ----------------
__global__ __launch_bounds__(256) void cvt_w(const float* __restrict__ Wq,
                                             const float* __restrict__ Wk,
                                             const float* __restrict__ Wv,
                                             ushort_t* __restrict__ wt) {
    const int z = blockIdx.z;
    const float* __restrict__ W = (z == 0) ? Wq : (z == 1) ? Wk : Wv;
    const int k0 = blockIdx.x * 64;
    const int n0 = blockIdx.y * 64;
    __shared__ float tile[64][65];
    const int t = threadIdx.x;
    {
        const int kk = t >> 2;            // 0..63
        const int c0 = (t & 3) * 16;      // 0,16,32,48
#pragma unroll
        for (int c = 0; c < 4; c++) {
            float4 v = *reinterpret_cast<const float4*>(&W[(size_t)(k0 + kk) * DD + n0 + c0 + c * 4]);
            tile[kk][c0 + c * 4 + 0] = v.x;
            tile[kk][c0 + c * 4 + 1] = v.y;
            tile[kk][c0 + c * 4 + 2] = v.z;
            tile[kk][c0 + c * 4 + 3] = v.w;
        }
    }
    __syncthreads();
    const int n = t >> 2;                 // 0..63
    const int kc = t & 3;                 // 0..3 -> 16 k each
    unsigned short tmp[16];
#pragma unroll
    for (int jj = 0; jj < 16; jj++) tmp[jj] = f2bf(tile[kc * 16 + jj][n]);
    uint4 u0, u1;
    u0.x = tmp[0] | (tmp[1] << 16);  u0.y = tmp[2] | (tmp[3] << 16);
    u0.z = tmp[4] | (tmp[5] << 16);  u0.w = tmp[6] | (tmp[7] << 16);
    u1.x = tmp[8] | (tmp[9] << 16);  u1.y = tmp[10] | (tmp[11] << 16);
    u1.z = tmp[12] | (tmp[13] << 16); u1.w = tmp[14] | (tmp[15] << 16);
    ushort_t* dst = &wt[((size_t)z << 20) + (size_t)(n0 + n) * DD + k0 + kc * 16];
    *reinterpret_cast<uint4*>(dst) = u0;
    *reinterpret_cast<uint4*>(dst + 8) = u1;
}

// ---------------- fused QKV bf16 MFMA GEMM ----------------
// C[m,n] = A[m,:] . Wt[n,:]  (+bias, elu+1 for q,k), out bf16 [bh][s][64].
// 128x128 tile, BK=32, 4 waves, m97 2-barrier structure w/ global_load_lds.
__global__ __launch_bounds__(256) void qkv_gemm_bf16(
    const ushort_t* __restrict__ A,    // [16384][1024] bf16
    const ushort_t* __restrict__ Bt,   // [3][1024 n][1024 k] bf16
    const float* __restrict__ bq, const float* __restrict__ bk, const float* __restrict__ bv,
    ushort_t* __restrict__ qf, ushort_t* __restrict__ kf, ushort_t* __restrict__ vf)
{
    const int z = blockIdx.z;
    const ushort_t* __restrict__ Bz = Bt + ((size_t)z << 20);
    const float* __restrict__ bias  = (z == 0) ? bq : (z == 1) ? bk : bv;
    ushort_t* __restrict__ out      = (z == 0) ? qf : (z == 1) ? kf : vf;

    const int n0 = blockIdx.x * 128;
    const int m0 = blockIdx.y * 128;

    __shared__ ushort_t As[128 * 32];
    __shared__ ushort_t Bs[128 * 32];

    const int tid = threadIdx.x;
    const int lane = tid & 63;
    const int w  = tid >> 6;       // wave 0..3
    const int wr = w >> 1;         // wave m-row 0/1
    const int wc = w & 1;          // wave n-col 0/1

    f32x4 acc[4][4];
#pragma unroll
    for (int i = 0; i < 4; i++)
#pragma unroll
        for (int j = 0; j < 4; j++) acc[i][j] = (f32x4){0.f, 0.f, 0.f, 0.f};

    const int lrow = lane >> 2;        // 0..15 row within 16-row segment
    const int lkc  = (lane & 3) * 8;   // k-elem offset 0,8,16,24

    const int fr = lane & 15;          // frag row/col index
    const int fk = (lane >> 4) * 8;    // frag k offset (elems)

    for (int k0 = 0; k0 < DD; k0 += 32) {
        __syncthreads();
#pragma unroll
        for (int si = 0; si < 2; si++) {
            const int seg = w * 2 + si;   // 0..7
            GLDS16(&A [(size_t)(m0 + seg * 16 + lrow) * DD + k0 + lkc], &As[seg * 512]);
            GLDS16(&Bz[(size_t)(n0 + seg * 16 + lrow) * DD + k0 + lkc], &Bs[seg * 512]);
        }
        __syncthreads();
        bf16x8 a[4], b[4];
#pragma unroll
        for (int i = 0; i < 4; i++)
            a[i] = *reinterpret_cast<const bf16x8*>(&As[(wr * 64 + i * 16 + fr) * 32 + fk]);
#pragma unroll
        for (int j = 0; j < 4; j++)
            b[j] = *reinterpret_cast<const bf16x8*>(&Bs[(wc * 64 + j * 16 + fr) * 32 + fk]);
#pragma unroll
        for (int i = 0; i < 4; i++)
#pragma unroll
            for (int j = 0; j < 4; j++)
                acc[i][j] = __builtin_amdgcn_mfma_f32_16x16x32_bf16(a[i], b[j], acc[i][j], 0, 0, 0);
    }

    // epilogue: C/D layout col=lane&15, row=(lane>>4)*4+reg  [m89/m91 verified]
    const int fq = lane >> 4;
    float bias4[4];
#pragma unroll
    for (int j = 0; j < 4; j++) bias4[j] = bias[n0 + wc * 64 + j * 16 + fr];
    const bool isqk = (z < 2);
#pragma unroll
    for (int i = 0; i < 4; i++) {
#pragma unroll
        for (int r = 0; r < 4; r++) {
            const int m = m0 + wr * 64 + i * 16 + fq * 4 + r;
            const int bI = m >> 12;          // batch
            const int s  = m & 4095;
#pragma unroll
            for (int j = 0; j < 4; j++) {
                const int n = n0 + wc * 64 + j * 16 + fr;
                const int h = n >> 6, e = n & 63;
                float c = acc[i][j][r] + bias4[j];
                if (isqk) c = (c > 0.f) ? (c + 1.f) : __expf(c);
                out[((size_t)(bI * HH + h) * SS + s) * HDD + e] = f2bf(c);
            }
        }
    }
}

// ---------------- kv[bh][d][e] += sum_s k[s,d]*v[s,e]; ksum[bh][d] ----------------
// grid (64 bh, 16 chunks of 256 s), block 256; 4x4 per-thread outer product.
__global__ __launch_bounds__(256) void kv_ksum2(
    const ushort_t* __restrict__ kf, const ushort_t* __restrict__ vf,
    float* __restrict__ kv, float* __restrict__ ksum)
{
    const int bh = blockIdx.x;
    const int s0 = blockIdx.y * 256;

    __shared__ float kb[16][68];
    __shared__ float vb[16][68];

    const int tid = threadIdx.x;
    const int tx = tid & 15;       // e group
    const int ty = tid >> 4;       // d group

    float acc[4][4] = {};
    float ks4[4] = {};

    const ushort_t* kbase = kf + (size_t)bh * SS * HDD;
    const ushort_t* vbase = vf + (size_t)bh * SS * HDD;

    for (int s = s0; s < s0 + 256; s += 16) {
        __syncthreads();
        {
            int t = tid;
            const ushort_t* src = kbase;
            float (*dst)[68] = kb;
            if (t >= 128) { t -= 128; src = vbase; dst = vb; }
            const int r = t >> 3;            // 0..15
            const int c = (t & 7) * 8;       // 0,8,..,56
            uint4 u = *reinterpret_cast<const uint4*>(&src[(size_t)(s + r) * HDD + c]);
            float4 f0 = make_float4(bf2f(u.x & 0xffff), bf2f(u.x >> 16),
                                    bf2f(u.y & 0xffff), bf2f(u.y >> 16));
            float4 f1 = make_float4(bf2f(u.z & 0xffff), bf2f(u.z >> 16),
                                    bf2f(u.w & 0xffff), bf2f(u.w >> 16));
            *reinterpret_cast<float4*>(&dst[r][c])     = f0;
            *reinterpret_cast<float4*>(&dst[r][c + 4]) = f1;
        }
        __syncthreads();
#pragma unroll
        for (int ss = 0; ss < 16; ss++) {
            float4 a = *reinterpret_cast<const float4*>(&kb[ss][ty * 4]);
            float4 b = *reinterpret_cast<const float4*>(&vb[ss][tx * 4]);
            const float av[4] = {a.x, a.y, a.z, a.w};
            const float bv4[4] = {b.x, b.y, b.z, b.w};
#pragma unroll
            for (int i = 0; i < 4; i++)
#pragma unroll
                for (int j = 0; j < 4; j++)
                    acc[i][j] += av[i] * bv4[j];
            if (tx == 0) {
#pragma unroll
                for (int i = 0; i < 4; i++) ks4[i] += av[i];
            }
        }
    }

    float* kvp = kv + (size_t)bh * HDD * HDD;
#pragma unroll
    for (int i = 0; i < 4; i++)
#pragma unroll
        for (int j = 0; j < 4; j++)
            atomicAdd(&kvp[(ty * 4 + i) * HDD + tx * 4 + j], acc[i][j]);
    if (tx == 0) {
#pragma unroll
        for (int i = 0; i < 4; i++)
            atomicAdd(&ksum[bh * HDD + ty * 4 + i], ks4[i]);
    }
}

// ---------------- out = (q_feat @ kv) / max(q_feat . ksum, eps) ----------------
// grid (64 bh, 64 s-blocks of 64), block 256; per-thread 4x4 micro-tile.
__global__ __launch_bounds__(256) void out2(
    const ushort_t* __restrict__ qf, const float* __restrict__ kv,
    const float* __restrict__ ksum, float* __restrict__ outp)
{
    const int bh = blockIdx.x;
    const int s0 = blockIdx.y * 64;
    const int bI = bh >> 4, h = bh & 15;

    __shared__ float kvs[64][64];    // [d][e]
    __shared__ float qsT[64][68];    // [d][s]  (transposed q tile)
    __shared__ float kss[64];
    __shared__ float denp[64][4];
    __shared__ float dens[64];

    const int tid = threadIdx.x;

    {   // kv tile: 4096 floats
        const float* kvg = kv + (size_t)bh * HDD * HDD;
        float* kvf = &kvs[0][0];
#pragma unroll
        for (int it = 0; it < 4; it++) {
            const int i = it * 1024 + tid * 4;
            *reinterpret_cast<float4*>(&kvf[i]) = *reinterpret_cast<const float4*>(&kvg[i]);
        }
        if (tid < 64) kss[tid] = ksum[bh * HDD + tid];
    }
    {   // q tile transpose: 64 rows x 64 e bf16 -> qsT[e][row]
        if (tid < 128) {
            const int r = tid >> 1;
            const int e0 = (tid & 1) * 32;
            const ushort_t* qb = qf + ((size_t)bh * SS + s0 + r) * HDD + e0;
#pragma unroll
            for (int q4 = 0; q4 < 4; q4++) {
                uint4 u = *reinterpret_cast<const uint4*>(&qb[q4 * 8]);
                const int eb = e0 + q4 * 8;
                qsT[eb + 0][r] = bf2f(u.x & 0xffff);
                qsT[eb + 1][r] = bf2f(u.x >> 16);
                qsT[eb + 2][r] = bf2f(u.y & 0xffff);
                qsT[eb + 3][r] = bf2f(u.y >> 16);
                qsT[eb + 4][r] = bf2f(u.z & 0xffff);
                qsT[eb + 5][r] = bf2f(u.z >> 16);
                qsT[eb + 6][r] = bf2f(u.w & 0xffff);
                qsT[eb + 7][r] = bf2f(u.w >> 16);
            }
        }
    }
    __syncthreads();

    {   // denominators: thread (s=tid>>2, dq=tid&3) partial over 16 d
        const int s = tid >> 2, dq = tid & 3;
        float p = 0.f;
#pragma unroll
        for (int ii = 0; ii < 16; ii++) {
            const int d = dq * 16 + ii;
            p += qsT[d][s] * kss[d];
        }
        denp[s][dq] = p;
    }
    __syncthreads();
    if (tid < 64)
        dens[tid] = fmaxf(denp[tid][0] + denp[tid][1] + denp[tid][2] + denp[tid][3], EPSV);
    __syncthreads();

    const int tx = tid & 15;    // e group
    const int ry = tid >> 4;    // row group
    float acc[4][4] = {};
    for (int d = 0; d < 64; d++) {
        float4 a = *reinterpret_cast<const float4*>(&qsT[d][ry * 4]);
        float4 b = *reinterpret_cast<const float4*>(&kvs[d][tx * 4]);
        const float av[4] = {a.x, a.y, a.z, a.w};
        const float bv4[4] = {b.x, b.y, b.z, b.w};
#pragma unroll
        for (int i = 0; i < 4; i++)
#pragma unroll
            for (int j = 0; j < 4; j++)
                acc[i][j] += av[i] * bv4[j];
    }

    float* ob = outp + ((size_t)(bI * SS + s0) * DD) + h * HDD;
#pragma unroll
    for (int i = 0; i < 4; i++) {
        const float inv = 1.0f / dens[ry * 4 + i];
        float4 o;
        o.x = acc[i][0] * inv; o.y = acc[i][1] * inv;
        o.z = acc[i][2] * inv; o.w = acc[i][3] * inv;
        *reinterpret_cast<float4*>(&ob[(size_t)(ry * 4 + i) * DD + tx * 4]) = o;
    }
}

extern "C" void kernel_launch(void* const* d_in, const int* in_sizes, int n_in,
                              void* d_out, int out_size, void* d_ws, size_t ws_size,
                              hipStream_t stream) {
    const float* hs = (const float*)d_in[0];
    const float* Wq = (const float*)d_in[1];
    const float* bq = (const float*)d_in[2];
    const float* Wk = (const float*)d_in[3];
    const float* bk = (const float*)d_in[4];
    const float* Wv = (const float*)d_in[5];
    const float* bv = (const float*)d_in[6];
    float* outp = (float*)d_out;

    // ws layout (~74.5 MB): hs_bf 32M | wt_bf 6M | qf 32M | kv 1M | ksum 16K
    ushort_t* hs_bf = (ushort_t*)d_ws;
    ushort_t* wt_bf = hs_bf + (size_t)MM * DD;
    ushort_t* qf    = wt_bf + ((size_t)3 << 20);
    float*    kvp   = (float*)(qf + (size_t)MM * DD);
    float*    ksum  = kvp + (size_t)BB * HH * HDD * HDD;
    // k_feat/v_feat (bf16, 32 MB each) live in d_out until out2 overwrites it.
    ushort_t* kf = (ushort_t*)d_out;
    ushort_t* vf = kf + (size_t)MM * DD;

    const int nz = BB * HH * HDD * HDD + BB * HH * HDD;
    hipLaunchKernelGGL(zero_kernel, dim3((nz + 255) / 256), dim3(256), 0, stream, kvp, nz);

    hipLaunchKernelGGL(cvt_hs, dim3((MM * DD) / (256 * 8)), dim3(256), 0, stream, hs, hs_bf);
    hipLaunchKernelGGL(cvt_w, dim3(16, 16, 3), dim3(256), 0, stream, Wq, Wk, Wv, wt_bf);

    dim3 g1(DD / 128, MM / 128, 3);
    hipLaunchKernelGGL(qkv_gemm_bf16, g1, dim3(256), 0, stream,
                       hs_bf, wt_bf, bq, bk, bv, qf, kf, vf);

    hipLaunchKernelGGL(kv_ksum2, dim3(BB * HH, 16), dim3(256), 0, stream, kf, vf, kvp, ksum);

    hipLaunchKernelGGL(out2, dim3(BB * HH, SS / 64), dim3(256), 0, stream, qf, kvp, ksum, outp);
}

// Round 6
// 342.053 us; speedup vs baseline: 4.3119x; 1.0847x over previous
//
#include <hip/hip_runtime.h>
#include <math.h>

#define BB 4
#define SS 4096
#define DD 1024
#define HH 16
#define HDD 64
#define MM (BB*SS)   // 16384
#define EPSV 1e-6f

typedef __bf16 bf16x8 __attribute__((ext_vector_type(8)));
typedef float  f32x4  __attribute__((ext_vector_type(4)));
typedef unsigned short ushort_t;

__device__ __forceinline__ float bf2f(unsigned int u16) {
    return __uint_as_float(u16 << 16);
}
__device__ __forceinline__ unsigned short f2bf(float f) {
    unsigned int x = __float_as_uint(f);
    unsigned int r = x + 0x7fffu + ((x >> 16) & 1u);  // RNE
    return (unsigned short)(r >> 16);
}

#define GLDS16(g, l) __builtin_amdgcn_global_load_lds( \
    (const __attribute__((address_space(1))) void*)(g), \
    (__attribute__((address_space(3))) void*)(l), 16, 0, 0)

// ---------------- hs fp32 -> bf16 ----------------
__global__ __launch_bounds__(256) void cvt_hs(const float* __restrict__ in,
                                              ushort_t* __restrict__ out) {
    size_t i = ((size_t)blockIdx.x * 256 + threadIdx.x) * 8;
    float4 f0 = *reinterpret_cast<const float4*>(&in[i]);
    float4 f1 = *reinterpret_cast<const float4*>(&in[i + 4]);
    uint4 u;
    u.x = (unsigned)f2bf(f0.x) | ((unsigned)f2bf(f0.y) << 16);
    u.y = (unsigned)f2bf(f0.z) | ((unsigned)f2bf(f0.w) << 16);
    u.z = (unsigned)f2bf(f1.x) | ((unsigned)f2bf(f1.y) << 16);
    u.w = (unsigned)f2bf(f1.z) | ((unsigned)f2bf(f1.w) << 16);
    *reinterpret_cast<uint4*>(&out[i]) = u;
}

// ---------------- W [K][N] fp32 -> Wt [z][N][K] bf16 ----------------
__global__ __launch_bounds__(256) void cvt_w(const float* __restrict__ Wq,
                                             const float* __restrict__ Wk,
                                             const float* __restrict__ Wv,
                                             ushort_t* __restrict__ wt) {
    const int z = blockIdx.z;
    const float* __restrict__ W = (z == 0) ? Wq : (z == 1) ? Wk : Wv;
    const int k0 = blockIdx.x * 64;
    const int n0 = blockIdx.y * 64;
    __shared__ float tile[64][65];
    const int t = threadIdx.x;
    {
        const int kk = t >> 2;
        const int c0 = (t & 3) * 16;
#pragma unroll
        for (int c = 0; c < 4; c++) {
            float4 v = *reinterpret_cast<const float4*>(&W[(size_t)(k0 + kk) * DD + n0 + c0 + c * 4]);
            tile[kk][c0 + c * 4 + 0] = v.x;
            tile[kk][c0 + c * 4 + 1] = v.y;
            tile[kk][c0 + c * 4 + 2] = v.z;
            tile[kk][c0 + c * 4 + 3] = v.w;
        }
    }
    __syncthreads();
    const int n = t >> 2;
    const int kc = t & 3;
    unsigned short tmp[16];
#pragma unroll
    for (int jj = 0; jj < 16; jj++) tmp[jj] = f2bf(tile[kc * 16 + jj][n]);
    uint4 u0, u1;
    u0.x = tmp[0] | (tmp[1] << 16);  u0.y = tmp[2] | (tmp[3] << 16);
    u0.z = tmp[4] | (tmp[5] << 16);  u0.w = tmp[6] | (tmp[7] << 16);
    u1.x = tmp[8] | (tmp[9] << 16);  u1.y = tmp[10] | (tmp[11] << 16);
    u1.z = tmp[12] | (tmp[13] << 16); u1.w = tmp[14] | (tmp[15] << 16);
    ushort_t* dst = &wt[((size_t)z << 20) + (size_t)(n0 + n) * DD + k0 + kc * 16];
    *reinterpret_cast<uint4*>(dst) = u0;
    *reinterpret_cast<uint4*>(dst + 8) = u1;
}

// ---------------- fused QKV bf16 MFMA GEMM ----------------
// 1D grid 3072 blocks, chunked XCD swizzle (n fastest within chunk).
// q -> [bh][s][d] bf16; k,v -> TRANSPOSED [bh][dim][s] bf16.
__global__ __launch_bounds__(256) void qkv_gemm_bf16(
    const ushort_t* __restrict__ A,    // [16384][1024] bf16
    const ushort_t* __restrict__ Bt,   // [3][1024 n][1024 k] bf16
    const float* __restrict__ bq, const float* __restrict__ bk, const float* __restrict__ bv,
    ushort_t* __restrict__ qf, ushort_t* __restrict__ kt, ushort_t* __restrict__ vt)
{
    // bijective chunked XCD swizzle: 3072 blocks, 8 XCDs, 384/chunk
    const int id  = blockIdx.x;
    const int swz = (id & 7) * 384 + (id >> 3);
    const int z   = swz >> 10;           // 0..2
    const int rem = swz & 1023;
    const int m0  = (rem >> 3) * 128;
    const int n0  = (rem & 7) * 128;

    const ushort_t* __restrict__ Bz = Bt + ((size_t)z << 20);
    const float* __restrict__ bias  = (z == 0) ? bq : (z == 1) ? bk : bv;

    __shared__ ushort_t As[128 * 32];
    __shared__ ushort_t Bs[128 * 32];

    const int tid = threadIdx.x;
    const int lane = tid & 63;
    const int w  = tid >> 6;
    const int wr = w >> 1;
    const int wc = w & 1;

    f32x4 acc[4][4];
#pragma unroll
    for (int i = 0; i < 4; i++)
#pragma unroll
        for (int j = 0; j < 4; j++) acc[i][j] = (f32x4){0.f, 0.f, 0.f, 0.f};

    const int lrow = lane >> 2;
    const int lkc  = (lane & 3) * 8;
    const int fr = lane & 15;
    const int fk = (lane >> 4) * 8;

    for (int k0 = 0; k0 < DD; k0 += 32) {
        __syncthreads();
#pragma unroll
        for (int si = 0; si < 2; si++) {
            const int seg = w * 2 + si;
            GLDS16(&A [(size_t)(m0 + seg * 16 + lrow) * DD + k0 + lkc], &As[seg * 512]);
            GLDS16(&Bz[(size_t)(n0 + seg * 16 + lrow) * DD + k0 + lkc], &Bs[seg * 512]);
        }
        __syncthreads();
        bf16x8 a[4], b[4];
#pragma unroll
        for (int i = 0; i < 4; i++)
            a[i] = *reinterpret_cast<const bf16x8*>(&As[(wr * 64 + i * 16 + fr) * 32 + fk]);
#pragma unroll
        for (int j = 0; j < 4; j++)
            b[j] = *reinterpret_cast<const bf16x8*>(&Bs[(wc * 64 + j * 16 + fr) * 32 + fk]);
#pragma unroll
        for (int i = 0; i < 4; i++)
#pragma unroll
            for (int j = 0; j < 4; j++)
                acc[i][j] = __builtin_amdgcn_mfma_f32_16x16x32_bf16(a[i], b[j], acc[i][j], 0, 0, 0);
    }

    // C/D layout: col = lane&15 (n), row = (lane>>4)*4 + reg (m)
    const int fq = lane >> 4;
    float bias4[4];
#pragma unroll
    for (int j = 0; j < 4; j++) bias4[j] = bias[n0 + wc * 64 + j * 16 + fr];

    if (z == 0) {
        // q: [bh][s][d], elu+1, scalar 2B stores (16-lane 32B segments)
#pragma unroll
        for (int i = 0; i < 4; i++) {
#pragma unroll
            for (int r = 0; r < 4; r++) {
                const int m = m0 + wr * 64 + i * 16 + fq * 4 + r;
                const int bI = m >> 12;
                const int s  = m & 4095;
#pragma unroll
                for (int j = 0; j < 4; j++) {
                    const int n = n0 + wc * 64 + j * 16 + fr;
                    const int h = n >> 6, e = n & 63;
                    float c = acc[i][j][r] + bias4[j];
                    c = (c > 0.f) ? (c + 1.f) : __expf(c);
                    qf[((size_t)(bI * HH + h) * SS + s) * HDD + e] = f2bf(c);
                }
            }
        }
    } else {
        // k/v: transposed [bh][dim][s]; 4 consecutive s per lane -> ushort4
        ushort_t* __restrict__ outt = (z == 1) ? kt : vt;
        const bool isk = (z == 1);
#pragma unroll
        for (int i = 0; i < 4; i++) {
            const int m = m0 + wr * 64 + i * 16 + fq * 4;
            const int bI = m >> 12;
            const int s  = m & 4095;
#pragma unroll
            for (int j = 0; j < 4; j++) {
                const int n = n0 + wc * 64 + j * 16 + fr;
                const int h = n >> 6, e = n & 63;
                ushort4 u;
                float c0 = acc[i][j][0] + bias4[j];
                float c1 = acc[i][j][1] + bias4[j];
                float c2 = acc[i][j][2] + bias4[j];
                float c3 = acc[i][j][3] + bias4[j];
                if (isk) {
                    c0 = (c0 > 0.f) ? (c0 + 1.f) : __expf(c0);
                    c1 = (c1 > 0.f) ? (c1 + 1.f) : __expf(c1);
                    c2 = (c2 > 0.f) ? (c2 + 1.f) : __expf(c2);
                    c3 = (c3 > 0.f) ? (c3 + 1.f) : __expf(c3);
                }
                u.x = f2bf(c0); u.y = f2bf(c1); u.z = f2bf(c2); u.w = f2bf(c3);
                *reinterpret_cast<ushort4*>(
                    &outt[((size_t)((bI * HH + h) * HDD + e)) * SS + s]) = u;
            }
        }
    }
}

// ---------------- kv partials via MFMA ----------------
// C[d][e] = sum_s Kt[d][s]*Vt[e][s] per (bh, s-chunk of 512). No LDS, no atomics.
// ksum via MFMA with B = ones (all output cols identical).
__global__ __launch_bounds__(256) void kv_mfma(
    const ushort_t* __restrict__ kt, const ushort_t* __restrict__ vt,
    float* __restrict__ kv_part, float* __restrict__ ksum_part)
{
    const int bh = blockIdx.x;
    const int c  = blockIdx.y;          // 0..7
    const int tid = threadIdx.x;
    const int lane = tid & 63;
    const int w = tid >> 6;
    const int fr = lane & 15;
    const int fq = lane >> 4;

    const size_t base = (size_t)bh * HDD * SS;
    const int s0 = c * 512;

    bf16x8 ones;
#pragma unroll
    for (int x = 0; x < 8; x++) ones[x] = (__bf16)1.0f;

    f32x4 acc[4], ks[4];
#pragma unroll
    for (int i = 0; i < 4; i++) { acc[i] = (f32x4){0,0,0,0}; ks[i] = (f32x4){0,0,0,0}; }

#pragma unroll
    for (int ksi = 0; ksi < 16; ksi++) {
        const int sc = s0 + ksi * 32 + fq * 8;
        bf16x8 a[4];
#pragma unroll
        for (int i = 0; i < 4; i++)
            a[i] = *reinterpret_cast<const bf16x8*>(&kt[base + (size_t)(i * 16 + fr) * SS + sc]);
        bf16x8 b = *reinterpret_cast<const bf16x8*>(&vt[base + (size_t)(w * 16 + fr) * SS + sc]);
#pragma unroll
        for (int i = 0; i < 4; i++) {
            acc[i] = __builtin_amdgcn_mfma_f32_16x16x32_bf16(a[i], b, acc[i], 0, 0, 0);
            ks[i]  = __builtin_amdgcn_mfma_f32_16x16x32_bf16(a[i], ones, ks[i], 0, 0, 0);
        }
    }

    float* kp = kv_part + ((size_t)(bh * 8 + c) << 12);
#pragma unroll
    for (int i = 0; i < 4; i++)
#pragma unroll
        for (int r = 0; r < 4; r++)
            kp[(i * 16 + fq * 4 + r) * 64 + (w * 16 + fr)] = acc[i][r];
    if (w == 0 && fr == 0) {
        float* ksp = ksum_part + (size_t)(bh * 8 + c) * 64;
#pragma unroll
        for (int i = 0; i < 4; i++)
#pragma unroll
            for (int r = 0; r < 4; r++)
                ksp[i * 16 + fq * 4 + r] = ks[i][r];
    }
}

// ---------------- finalize: sum partials, hi/lo bf16 split, transpose ----------------
// kv [d][e] fp32 -> kvh/kvl [bh][e][d] bf16; ksum fp32.
__global__ __launch_bounds__(256) void kv_finalize(
    const float* __restrict__ kv_part, const float* __restrict__ ksum_part,
    ushort_t* __restrict__ kvh, ushort_t* __restrict__ kvl, float* __restrict__ ksum)
{
    const int bh = blockIdx.x;
    const int tid = threadIdx.x;
    __shared__ float lin[4096];

    const float* kp = kv_part + ((size_t)(bh * 8) << 12);
    float s[16];
#pragma unroll
    for (int x = 0; x < 16; x++) s[x] = 0.f;
#pragma unroll
    for (int cc = 0; cc < 8; cc++) {
#pragma unroll
        for (int g = 0; g < 4; g++) {
            float4 v = *reinterpret_cast<const float4*>(&kp[((size_t)cc << 12) + tid * 16 + g * 4]);
            s[g * 4 + 0] += v.x; s[g * 4 + 1] += v.y;
            s[g * 4 + 2] += v.z; s[g * 4 + 3] += v.w;
        }
    }
#pragma unroll
    for (int g = 0; g < 4; g++) {
        float4 v = make_float4(s[g * 4], s[g * 4 + 1], s[g * 4 + 2], s[g * 4 + 3]);
        *reinterpret_cast<float4*>(&lin[tid * 16 + g * 4]) = v;
    }
    if (tid < 64) {
        float t = 0.f;
#pragma unroll
        for (int cc = 0; cc < 8; cc++) t += ksum_part[(size_t)(bh * 8 + cc) * 64 + tid];
        ksum[bh * 64 + tid] = t;
    }
    __syncthreads();

    const int e  = tid >> 2;
    const int db = tid & 3;
    ushort_t hi[16], lo[16];
#pragma unroll
    for (int dd = 0; dd < 16; dd++) {
        float v = lin[(db * 16 + dd) * 64 + e];
        hi[dd] = f2bf(v);
        lo[dd] = f2bf(v - bf2f(hi[dd]));
    }
    ushort_t* ph = &kvh[(size_t)bh * 4096 + e * 64 + db * 16];
    ushort_t* pl = &kvl[(size_t)bh * 4096 + e * 64 + db * 16];
#pragma unroll
    for (int g = 0; g < 2; g++) {
        uint4 uh, ul;
        uh.x = hi[g*8+0] | (hi[g*8+1] << 16); uh.y = hi[g*8+2] | (hi[g*8+3] << 16);
        uh.z = hi[g*8+4] | (hi[g*8+5] << 16); uh.w = hi[g*8+6] | (hi[g*8+7] << 16);
        ul.x = lo[g*8+0] | (lo[g*8+1] << 16); ul.y = lo[g*8+2] | (lo[g*8+3] << 16);
        ul.z = lo[g*8+4] | (lo[g*8+5] << 16); ul.w = lo[g*8+6] | (lo[g*8+7] << 16);
        *reinterpret_cast<uint4*>(ph + g * 8) = uh;
        *reinterpret_cast<uint4*>(pl + g * 8) = ul;
    }
}

// ---------------- out = (Q @ (kv_hi+kv_lo)) / max(Q . ksum, eps) ----------------
// grid (64 bh, 64 sblk). MFMA numerator (hi/lo split), fp32 VALU denominator.
__global__ __launch_bounds__(256) void out_mfma(
    const ushort_t* __restrict__ qf, const ushort_t* __restrict__ kvh,
    const ushort_t* __restrict__ kvl, const float* __restrict__ ksum,
    float* __restrict__ outp)
{
    const int bh = blockIdx.x;
    const int s0 = blockIdx.y * 64;
    const int bI = bh >> 4, h = bh & 15;
    const int tid = threadIdx.x;

    __shared__ float kss[64];
    __shared__ float denp[64][4];
    __shared__ float dens[64];

    if (tid < 64) kss[tid] = ksum[bh * 64 + tid];
    __syncthreads();

    {   // denominator: thread (sr, dq) does 16 d
        const int sr = tid >> 2, dq = tid & 3;
        const ushort_t* qp = qf + (size_t)bh * SS * HDD + (size_t)(s0 + sr) * HDD + dq * 16;
        uint4 u0 = *reinterpret_cast<const uint4*>(qp);
        uint4 u1 = *reinterpret_cast<const uint4*>(qp + 8);
        const float* kb = &kss[dq * 16];
        float p = 0.f;
        p += bf2f(u0.x & 0xffff) * kb[0];  p += bf2f(u0.x >> 16) * kb[1];
        p += bf2f(u0.y & 0xffff) * kb[2];  p += bf2f(u0.y >> 16) * kb[3];
        p += bf2f(u0.z & 0xffff) * kb[4];  p += bf2f(u0.z >> 16) * kb[5];
        p += bf2f(u0.w & 0xffff) * kb[6];  p += bf2f(u0.w >> 16) * kb[7];
        p += bf2f(u1.x & 0xffff) * kb[8];  p += bf2f(u1.x >> 16) * kb[9];
        p += bf2f(u1.y & 0xffff) * kb[10]; p += bf2f(u1.y >> 16) * kb[11];
        p += bf2f(u1.z & 0xffff) * kb[12]; p += bf2f(u1.z >> 16) * kb[13];
        p += bf2f(u1.w & 0xffff) * kb[14]; p += bf2f(u1.w >> 16) * kb[15];
        denp[sr][dq] = p;
    }
    __syncthreads();
    if (tid < 64)
        dens[tid] = fmaxf(denp[tid][0] + denp[tid][1] + denp[tid][2] + denp[tid][3], EPSV);
    __syncthreads();

    const int lane = tid & 63, w = tid >> 6;
    const int fr = lane & 15, fq = lane >> 4;

    // A-frags direct from global: rows s0 + w*16 + fr
    const ushort_t* qb = qf + (size_t)bh * SS * HDD + (size_t)(s0 + w * 16 + fr) * HDD + fq * 8;
    bf16x8 a0 = *reinterpret_cast<const bf16x8*>(qb);
    bf16x8 a1 = *reinterpret_cast<const bf16x8*>(qb + 32);

    f32x4 acc[4];
#pragma unroll
    for (int j = 0; j < 4; j++) acc[j] = (f32x4){0.f, 0.f, 0.f, 0.f};

    const ushort_t* hb = kvh + ((size_t)bh << 12) + (size_t)fr * HDD + fq * 8;
    const ushort_t* lb = kvl + ((size_t)bh << 12) + (size_t)fr * HDD + fq * 8;
#pragma unroll
    for (int j = 0; j < 4; j++) {
        const ushort_t* hj = hb + (size_t)j * 16 * HDD;
        const ushort_t* lj = lb + (size_t)j * 16 * HDD;
        bf16x8 bh0 = *reinterpret_cast<const bf16x8*>(hj);
        bf16x8 bh1 = *reinterpret_cast<const bf16x8*>(hj + 32);
        bf16x8 bl0 = *reinterpret_cast<const bf16x8*>(lj);
        bf16x8 bl1 = *reinterpret_cast<const bf16x8*>(lj + 32);
        acc[j] = __builtin_amdgcn_mfma_f32_16x16x32_bf16(a0, bh0, acc[j], 0, 0, 0);
        acc[j] = __builtin_amdgcn_mfma_f32_16x16x32_bf16(a1, bh1, acc[j], 0, 0, 0);
        acc[j] = __builtin_amdgcn_mfma_f32_16x16x32_bf16(a0, bl0, acc[j], 0, 0, 0);
        acc[j] = __builtin_amdgcn_mfma_f32_16x16x32_bf16(a1, bl1, acc[j], 0, 0, 0);
    }

#pragma unroll
    for (int r = 0; r < 4; r++) {
        const int srow = w * 16 + fq * 4 + r;
        const float inv = 1.0f / dens[srow];
        float* ob = outp + ((size_t)(bI * SS + s0 + srow)) * DD + h * HDD;
#pragma unroll
        for (int j = 0; j < 4; j++)
            ob[j * 16 + fr] = acc[j][r] * inv;
    }
}

extern "C" void kernel_launch(void* const* d_in, const int* in_sizes, int n_in,
                              void* d_out, int out_size, void* d_ws, size_t ws_size,
                              hipStream_t stream) {
    const float* hs = (const float*)d_in[0];
    const float* Wq = (const float*)d_in[1];
    const float* bq = (const float*)d_in[2];
    const float* Wk = (const float*)d_in[3];
    const float* bk = (const float*)d_in[4];
    const float* Wv = (const float*)d_in[5];
    const float* bv = (const float*)d_in[6];
    float* outp = (float*)d_out;

    // ws: hs_bf 32M | wt_bf 6M | qf 32M | kv_part 8M | ksum_part 128K | kvh 512K | kvl 512K | ksum 16K
    ushort_t* hs_bf    = (ushort_t*)d_ws;
    ushort_t* wt_bf    = hs_bf + (size_t)MM * DD;
    ushort_t* qf       = wt_bf + ((size_t)3 << 20);
    float*    kv_part  = (float*)(qf + (size_t)MM * DD);
    float*    ksum_prt = kv_part + ((size_t)64 * 8 << 12);
    ushort_t* kvh      = (ushort_t*)(ksum_prt + 64 * 8 * 64);
    ushort_t* kvl      = kvh + (size_t)64 * 4096;
    float*    ksum     = (float*)(kvl + (size_t)64 * 4096);
    // k_t / v_t (transposed bf16, 32MB each) live in d_out until out_mfma overwrites it
    ushort_t* kt = (ushort_t*)d_out;
    ushort_t* vt = kt + (size_t)MM * DD;

    hipLaunchKernelGGL(cvt_hs, dim3((MM * DD) / (256 * 8)), dim3(256), 0, stream, hs, hs_bf);
    hipLaunchKernelGGL(cvt_w, dim3(16, 16, 3), dim3(256), 0, stream, Wq, Wk, Wv, wt_bf);

    hipLaunchKernelGGL(qkv_gemm_bf16, dim3(3072), dim3(256), 0, stream,
                       hs_bf, wt_bf, bq, bk, bv, qf, kt, vt);

    hipLaunchKernelGGL(kv_mfma, dim3(64, 8), dim3(256), 0, stream, kt, vt, kv_part, ksum_prt);
    hipLaunchKernelGGL(kv_finalize, dim3(64), dim3(256), 0, stream,
                       kv_part, ksum_prt, kvh, kvl, ksum);
    hipLaunchKernelGGL(out_mfma, dim3(64, 64), dim3(256), 0, stream,
                       qf, kvh, kvl, ksum, outp);
}

// Round 9
// 337.153 us; speedup vs baseline: 4.3746x; 1.0145x over previous
//
#include <hip/hip_runtime.h>
#include <math.h>

#define BB 4
#define SS 4096
#define DD 1024
#define HH 16
#define HDD 64
#define MM (BB*SS)   // 16384
#define EPSV 1e-6f
#define CS 136       // LDS epilogue stride (ushorts): 272B, 16B-aligned rows

typedef __bf16 bf16x8 __attribute__((ext_vector_type(8)));
typedef float  f32x4  __attribute__((ext_vector_type(4)));
typedef unsigned short u16x8 __attribute__((ext_vector_type(8)));
typedef unsigned short ushort_t;

union BFU { u16x8 u; bf16x8 b; };

__device__ __forceinline__ float bf2f(unsigned int u16) {
    return __uint_as_float(u16 << 16);
}
__device__ __forceinline__ unsigned short f2bf(float f) {
    unsigned int x = __float_as_uint(f);
    unsigned int r = x + 0x7fffu + ((x >> 16) & 1u);  // RNE
    return (unsigned short)(r >> 16);
}

#define GLDS16(g, l) __builtin_amdgcn_global_load_lds( \
    (const __attribute__((address_space(1))) void*)(g), \
    (__attribute__((address_space(3))) void*)(l), 16, 0, 0)

// ---------------- hs fp32 -> bf16 ----------------
__global__ __launch_bounds__(256) void cvt_hs(const float* __restrict__ in,
                                              ushort_t* __restrict__ out) {
    size_t i = ((size_t)blockIdx.x * 256 + threadIdx.x) * 8;
    float4 f0 = *reinterpret_cast<const float4*>(&in[i]);
    float4 f1 = *reinterpret_cast<const float4*>(&in[i + 4]);
    uint4 u;
    u.x = (unsigned)f2bf(f0.x) | ((unsigned)f2bf(f0.y) << 16);
    u.y = (unsigned)f2bf(f0.z) | ((unsigned)f2bf(f0.w) << 16);
    u.z = (unsigned)f2bf(f1.x) | ((unsigned)f2bf(f1.y) << 16);
    u.w = (unsigned)f2bf(f1.z) | ((unsigned)f2bf(f1.w) << 16);
    *reinterpret_cast<uint4*>(&out[i]) = u;
}

// ---------------- W [K][N] fp32 -> Wt [z][N][K] bf16 ----------------
__global__ __launch_bounds__(256) void cvt_w(const float* __restrict__ Wq,
                                             const float* __restrict__ Wk,
                                             const float* __restrict__ Wv,
                                             ushort_t* __restrict__ wt) {
    const int z = blockIdx.z;
    const float* __restrict__ W = (z == 0) ? Wq : (z == 1) ? Wk : Wv;
    const int k0 = blockIdx.x * 64;
    const int n0 = blockIdx.y * 64;
    __shared__ float tile[64][65];
    const int t = threadIdx.x;
    {
        const int kk = t >> 2;
        const int c0 = (t & 3) * 16;
#pragma unroll
        for (int c = 0; c < 4; c++) {
            float4 v = *reinterpret_cast<const float4*>(&W[(size_t)(k0 + kk) * DD + n0 + c0 + c * 4]);
            tile[kk][c0 + c * 4 + 0] = v.x;
            tile[kk][c0 + c * 4 + 1] = v.y;
            tile[kk][c0 + c * 4 + 2] = v.z;
            tile[kk][c0 + c * 4 + 3] = v.w;
        }
    }
    __syncthreads();
    const int n = t >> 2;
    const int kc = t & 3;
    unsigned short tmp[16];
#pragma unroll
    for (int jj = 0; jj < 16; jj++) tmp[jj] = f2bf(tile[kc * 16 + jj][n]);
    uint4 u0, u1;
    u0.x = tmp[0] | (tmp[1] << 16);  u0.y = tmp[2] | (tmp[3] << 16);
    u0.z = tmp[4] | (tmp[5] << 16);  u0.w = tmp[6] | (tmp[7] << 16);
    u1.x = tmp[8] | (tmp[9] << 16);  u1.y = tmp[10] | (tmp[11] << 16);
    u1.z = tmp[12] | (tmp[13] << 16); u1.w = tmp[14] | (tmp[15] << 16);
    ushort_t* dst = &wt[((size_t)z << 20) + (size_t)(n0 + n) * DD + k0 + kc * 16];
    *reinterpret_cast<uint4*>(dst) = u0;
    *reinterpret_cast<uint4*>(dst + 8) = u1;
}

// ---------------- fused QKV bf16 MFMA GEMM, LDS-staged epilogue ----------------
// q -> [bh][s][64]; k,v -> transposed [bh][dim][S]. XCD-chunked swizzle.
__global__ __launch_bounds__(256) void qkv_gemm_bf16(
    const ushort_t* __restrict__ A,    // [16384][1024] bf16
    const ushort_t* __restrict__ Bt,   // [3][1024 n][1024 k] bf16
    const float* __restrict__ bq, const float* __restrict__ bk, const float* __restrict__ bv,
    ushort_t* __restrict__ qf, ushort_t* __restrict__ kt, ushort_t* __restrict__ vt)
{
    const int id  = blockIdx.x;
    const int swz = (id & 7) * 384 + (id >> 3);   // bijective: 3072 % 8 == 0
    const int z   = swz >> 10;
    const int rem = swz & 1023;
    const int m0  = (rem >> 3) * 128;
    const int n0  = (rem & 7) * 128;

    const ushort_t* __restrict__ Bz = Bt + ((size_t)z << 20);
    const float* __restrict__ bias  = (z == 0) ? bq : (z == 1) ? bk : bv;

    __shared__ ushort_t smem[128 * CS];   // 34 KB; K-loop uses first 16 KB as As|Bs
    ushort_t* As = smem;
    ushort_t* Bs = smem + 4096;

    const int tid = threadIdx.x;
    const int lane = tid & 63;
    const int w  = tid >> 6;
    const int wr = w >> 1;
    const int wc = w & 1;

    f32x4 acc[4][4];
#pragma unroll
    for (int i = 0; i < 4; i++)
#pragma unroll
        for (int j = 0; j < 4; j++) acc[i][j] = (f32x4){0.f, 0.f, 0.f, 0.f};

    const int lrow = lane >> 2;
    const int lkc  = (lane & 3) * 8;
    const int fr = lane & 15;
    const int fk = (lane >> 4) * 8;

    for (int k0 = 0; k0 < DD; k0 += 32) {
        __syncthreads();
#pragma unroll
        for (int si = 0; si < 2; si++) {
            const int seg = w * 2 + si;
            GLDS16(&A [(size_t)(m0 + seg * 16 + lrow) * DD + k0 + lkc], &As[seg * 512]);
            GLDS16(&Bz[(size_t)(n0 + seg * 16 + lrow) * DD + k0 + lkc], &Bs[seg * 512]);
        }
        __syncthreads();
        bf16x8 a[4], b[4];
#pragma unroll
        for (int i = 0; i < 4; i++)
            a[i] = *reinterpret_cast<const bf16x8*>(&As[(wr * 64 + i * 16 + fr) * 32 + fk]);
#pragma unroll
        for (int j = 0; j < 4; j++)
            b[j] = *reinterpret_cast<const bf16x8*>(&Bs[(wc * 64 + j * 16 + fr) * 32 + fk]);
#pragma unroll
        for (int i = 0; i < 4; i++)
#pragma unroll
            for (int j = 0; j < 4; j++)
                acc[i][j] = __builtin_amdgcn_mfma_f32_16x16x32_bf16(a[i], b[j], acc[i][j], 0, 0, 0);
    }

    __syncthreads();   // all frag ds_reads done before Cs overwrite

    // stage C tile into LDS (bias + activation fused)
    const int fq = lane >> 4;
    float bias4[4];
#pragma unroll
    for (int j = 0; j < 4; j++) bias4[j] = bias[n0 + wc * 64 + j * 16 + fr];

    if (z == 0) {
#pragma unroll
        for (int i = 0; i < 4; i++)
#pragma unroll
            for (int r = 0; r < 4; r++) {
                const int row = wr * 64 + i * 16 + fq * 4 + r;
#pragma unroll
                for (int j = 0; j < 4; j++) {
                    const int col = wc * 64 + j * 16 + fr;
                    float c = acc[i][j][r] + bias4[j];
                    c = (c > 0.f) ? (c + 1.f) : __expf(c);
                    smem[row * CS + col] = f2bf(c);
                }
            }
    } else {
        const bool isk = (z == 1);
#pragma unroll
        for (int i = 0; i < 4; i++)
#pragma unroll
            for (int r = 0; r < 4; r++) {
                const int row = wr * 64 + i * 16 + fq * 4 + r;
#pragma unroll
                for (int j = 0; j < 4; j++) {
                    const int col = wc * 64 + j * 16 + fr;
                    float c = acc[i][j][r] + bias4[j];
                    if (isk) c = (c > 0.f) ? (c + 1.f) : __expf(c);
                    smem[col * CS + row] = f2bf(c);   // transposed
                }
            }
    }
    __syncthreads();

    // vector stores: 128B per lane, wave-contiguous (q) / full-line strided (k,v)
    const int rowh = tid & 127;
    const int half = tid >> 7;
    const int bI = m0 >> 12;
    const ushort_t* src = &smem[rowh * CS + half * 64];

    if (z == 0) {
        const int s = (m0 & 4095) + rowh;
        const int h = (n0 >> 6) + half;
        ushort_t* dst = &qf[((size_t)(bI * HH + h) * SS + s) * HDD];
#pragma unroll
        for (int g = 0; g < 8; g++)
            *reinterpret_cast<uint4*>(dst + g * 8) = *reinterpret_cast<const uint4*>(src + g * 8);
    } else {
        ushort_t* __restrict__ outt = (z == 1) ? kt : vt;
        const int n = n0 + rowh;
        const int h = n >> 6, e = n & 63;
        const int sb = (m0 & 4095) + half * 64;
        ushort_t* dst = &outt[((size_t)((bI * HH + h) * HDD + e)) * SS + sb];
#pragma unroll
        for (int g = 0; g < 8; g++)
            *reinterpret_cast<uint4*>(dst + g * 8) = *reinterpret_cast<const uint4*>(src + g * 8);
    }
}

// ---------------- kv partials via MFMA ----------------
__global__ __launch_bounds__(256) void kv_mfma(
    const ushort_t* __restrict__ kt, const ushort_t* __restrict__ vt,
    float* __restrict__ kv_part, float* __restrict__ ksum_part)
{
    const int bh = blockIdx.x;
    const int c  = blockIdx.y;          // 0..7
    const int tid = threadIdx.x;
    const int lane = tid & 63;
    const int w = tid >> 6;
    const int fr = lane & 15;
    const int fq = lane >> 4;

    const size_t base = (size_t)bh * HDD * SS;
    const int s0 = c * 512;

    bf16x8 ones;
#pragma unroll
    for (int x = 0; x < 8; x++) ones[x] = (__bf16)1.0f;

    f32x4 acc[4], ks[4];
#pragma unroll
    for (int i = 0; i < 4; i++) { acc[i] = (f32x4){0,0,0,0}; ks[i] = (f32x4){0,0,0,0}; }

#pragma unroll
    for (int ksi = 0; ksi < 16; ksi++) {
        const int sc = s0 + ksi * 32 + fq * 8;
        bf16x8 a[4];
#pragma unroll
        for (int i = 0; i < 4; i++)
            a[i] = *reinterpret_cast<const bf16x8*>(&kt[base + (size_t)(i * 16 + fr) * SS + sc]);
        bf16x8 b = *reinterpret_cast<const bf16x8*>(&vt[base + (size_t)(w * 16 + fr) * SS + sc]);
#pragma unroll
        for (int i = 0; i < 4; i++) {
            acc[i] = __builtin_amdgcn_mfma_f32_16x16x32_bf16(a[i], b, acc[i], 0, 0, 0);
            ks[i]  = __builtin_amdgcn_mfma_f32_16x16x32_bf16(a[i], ones, ks[i], 0, 0, 0);
        }
    }

    float* kp = kv_part + ((size_t)(bh * 8 + c) << 12);
#pragma unroll
    for (int i = 0; i < 4; i++)
#pragma unroll
        for (int r = 0; r < 4; r++)
            kp[(i * 16 + fq * 4 + r) * 64 + (w * 16 + fr)] = acc[i][r];
    if (w == 0 && fr == 0) {
        float* ksp = ksum_part + (size_t)(bh * 8 + c) * 64;
#pragma unroll
        for (int i = 0; i < 4; i++)
#pragma unroll
            for (int r = 0; r < 4; r++)
                ksp[i * 16 + fq * 4 + r] = ks[i][r];
    }
}

// ---------------- fused: reduce partials + hi/lo + num/den MFMA + divide ----------------
// grid (64 bh, 64 sblk of 64 rows). Denominator via MFMA with ksum hi/lo columns.
__global__ __launch_bounds__(256) void out_fused(
    const ushort_t* __restrict__ qf, const float* __restrict__ kv_part,
    const float* __restrict__ ksum_part, float* __restrict__ outp)
{
    const int bh = blockIdx.x;
    const int s0 = blockIdx.y * 64;
    const int bI = bh >> 4, h = bh & 15;
    const int tid = threadIdx.x;

    __shared__ float kvf[64 * 65];   // [d][e], +1 pad
    __shared__ float kss[64];

    {   // reduce the 8 kv partials
        const int d  = tid >> 2;
        const int eg = (tid & 3) * 16;
        float s16[16];
#pragma unroll
        for (int x = 0; x < 16; x++) s16[x] = 0.f;
#pragma unroll
        for (int c = 0; c < 8; c++) {
            const float* kp = kv_part + (((size_t)(bh * 8 + c)) << 12) + d * 64 + eg;
#pragma unroll
            for (int g = 0; g < 4; g++) {
                float4 v = *reinterpret_cast<const float4*>(&kp[g * 4]);
                s16[g * 4 + 0] += v.x; s16[g * 4 + 1] += v.y;
                s16[g * 4 + 2] += v.z; s16[g * 4 + 3] += v.w;
            }
        }
#pragma unroll
        for (int x = 0; x < 16; x++) kvf[d * 65 + eg + x] = s16[x];
        if (tid < 64) {
            float t = 0.f;
#pragma unroll
            for (int c = 0; c < 8; c++) t += ksum_part[(size_t)(bh * 8 + c) * 64 + tid];
            kss[tid] = t;
        }
    }
    __syncthreads();

    const int lane = tid & 63, w = tid >> 6;
    const int fr = lane & 15, fq = lane >> 4;

    // A-frags: q rows s0 + w*16 + fr
    const ushort_t* qb = qf + ((size_t)bh * SS + s0 + w * 16 + fr) * HDD + fq * 8;
    bf16x8 a0 = *reinterpret_cast<const bf16x8*>(qb);
    bf16x8 a1 = *reinterpret_cast<const bf16x8*>(qb + 32);

    // den B-frags: broadcast ksum hi/lo columns
    BFU kh0, kh1, kl0, kl1;
#pragma unroll
    for (int t = 0; t < 8; t++) {
        float v0 = kss[fq * 8 + t];
        float v1 = kss[32 + fq * 8 + t];
        unsigned short h0 = f2bf(v0), h1 = f2bf(v1);
        kh0.u[t] = h0; kl0.u[t] = f2bf(v0 - bf2f(h0));
        kh1.u[t] = h1; kl1.u[t] = f2bf(v1 - bf2f(h1));
    }

    f32x4 accn[4], accd;
#pragma unroll
    for (int j = 0; j < 4; j++) accn[j] = (f32x4){0.f, 0.f, 0.f, 0.f};
    accd = (f32x4){0.f, 0.f, 0.f, 0.f};

    accd = __builtin_amdgcn_mfma_f32_16x16x32_bf16(a0, kh0.b, accd, 0, 0, 0);
    accd = __builtin_amdgcn_mfma_f32_16x16x32_bf16(a1, kh1.b, accd, 0, 0, 0);
    accd = __builtin_amdgcn_mfma_f32_16x16x32_bf16(a0, kl0.b, accd, 0, 0, 0);
    accd = __builtin_amdgcn_mfma_f32_16x16x32_bf16(a1, kl1.b, accd, 0, 0, 0);

#pragma unroll
    for (int j = 0; j < 4; j++) {
        const int e = j * 16 + fr;
        BFU bh0, bh1, bl0, bl1;
#pragma unroll
        for (int t = 0; t < 8; t++) {
            float v0 = kvf[(fq * 8 + t) * 65 + e];
            float v1 = kvf[(32 + fq * 8 + t) * 65 + e];
            unsigned short h0 = f2bf(v0), h1 = f2bf(v1);
            bh0.u[t] = h0; bl0.u[t] = f2bf(v0 - bf2f(h0));
            bh1.u[t] = h1; bl1.u[t] = f2bf(v1 - bf2f(h1));
        }
        accn[j] = __builtin_amdgcn_mfma_f32_16x16x32_bf16(a0, bh0.b, accn[j], 0, 0, 0);
        accn[j] = __builtin_amdgcn_mfma_f32_16x16x32_bf16(a1, bh1.b, accn[j], 0, 0, 0);
        accn[j] = __builtin_amdgcn_mfma_f32_16x16x32_bf16(a0, bl0.b, accn[j], 0, 0, 0);
        accn[j] = __builtin_amdgcn_mfma_f32_16x16x32_bf16(a1, bl1.b, accn[j], 0, 0, 0);
    }

#pragma unroll
    for (int r = 0; r < 4; r++) {
        const int srow = w * 16 + fq * 4 + r;
        const float inv = 1.0f / fmaxf(accd[r], EPSV);
        float* ob = outp + ((size_t)(bI * SS + s0 + srow)) * DD + h * HDD;
#pragma unroll
        for (int j = 0; j < 4; j++)
            ob[j * 16 + fr] = accn[j][r] * inv;
    }
}

extern "C" void kernel_launch(void* const* d_in, const int* in_sizes, int n_in,
                              void* d_out, int out_size, void* d_ws, size_t ws_size,
                              hipStream_t stream) {
    const float* hs = (const float*)d_in[0];
    const float* Wq = (const float*)d_in[1];
    const float* bq = (const float*)d_in[2];
    const float* Wk = (const float*)d_in[3];
    const float* bk = (const float*)d_in[4];
    const float* Wv = (const float*)d_in[5];
    const float* bv = (const float*)d_in[6];
    float* outp = (float*)d_out;

    // ws: hs_bf 32M | wt_bf 6M | qf 32M | kv_part 8M | ksum_part 128K  (~78 MB)
    ushort_t* hs_bf    = (ushort_t*)d_ws;
    ushort_t* wt_bf    = hs_bf + (size_t)MM * DD;
    ushort_t* qf       = wt_bf + ((size_t)3 << 20);
    float*    kv_part  = (float*)(qf + (size_t)MM * DD);
    float*    ksum_prt = kv_part + ((size_t)64 * 8 << 12);
    // k_t / v_t (transposed bf16, 32MB each) live in d_out until out_fused overwrites it
    ushort_t* kt = (ushort_t*)d_out;
    ushort_t* vt = kt + (size_t)MM * DD;

    hipLaunchKernelGGL(cvt_hs, dim3((MM * DD) / (256 * 8)), dim3(256), 0, stream, hs, hs_bf);
    hipLaunchKernelGGL(cvt_w, dim3(16, 16, 3), dim3(256), 0, stream, Wq, Wk, Wv, wt_bf);

    hipLaunchKernelGGL(qkv_gemm_bf16, dim3(3072), dim3(256), 0, stream,
                       hs_bf, wt_bf, bq, bk, bv, qf, kt, vt);

    hipLaunchKernelGGL(kv_mfma, dim3(64, 8), dim3(256), 0, stream, kt, vt, kv_part, ksum_prt);
    hipLaunchKernelGGL(out_fused, dim3(64, 64), dim3(256), 0, stream,
                       qf, kv_part, ksum_prt, outp);
}